// Round 1
// baseline (31.119 us; speedup 1.0000x reference)
//
#include <hip/hip_runtime.h>
#include <math.h>

// Problem constants (from reference setup_inputs): B=2, S=1024, F=512, N=128.
#define F 512
#define N 128
#define ROWS_PER_BLOCK 4

constexpr float PROB_THRESHOLD = 0.3f;
constexpr float INV_SQRT_2PI   = 0.3989422804014327f;
// exp(-0.5*z^2) = exp2(-(z*SCALE_C)^2), SCALE_C = sqrt(0.5*log2(e))
constexpr float SCALE_C = 0.8493218002880191f;
// 128^(-0.2)  (Scott's rule factor, matches f32 rounding of the double value)
constexpr float FACTOR  = 0.37892914162759955f;

// ---------------------------------------------------------------------------
// Kernel 1: per-feature bandwidth stats.
// scale[f] = SCALE_C / bw,  coef[f] = INV_SQRT_2PI / bw
// Two-pass variance (ddof=1) to match jnp.std's numerical behavior.
// ---------------------------------------------------------------------------
__global__ void kde_stats(const float* __restrict__ kde,
                          float* __restrict__ scale,
                          float* __restrict__ coef) {
    const int f = threadIdx.x;  // launched with F threads
    float s = 0.f;
    for (int n = 0; n < N; ++n) s += kde[n * F + f];
    const float mean = s * (1.0f / N);
    float ss = 0.f;
    for (int n = 0; n < N; ++n) {
        const float d = kde[n * F + f] - mean;
        ss = fmaf(d, d, ss);
    }
    const float var = ss * (1.0f / (N - 1));
    const float bw  = FACTOR * sqrtf(var);
    scale[f] = SCALE_C / bw;
    coef[f]  = INV_SQRT_2PI / bw;
}

// ---------------------------------------------------------------------------
// Kernel 2: main KDE-mask kernel.
// Block = 512 threads (one per feature), handles ROWS_PER_BLOCK rows.
// Inner loop per kde sample n: 1 coalesced load + 1 mul, then per row:
// sub, mul, v_exp_f32 (negate folded as input modifier), add.
// ---------------------------------------------------------------------------
template <bool INLINE_STATS>
__global__ __launch_bounds__(F) void kde_mask(const float* __restrict__ x,
                                              const float* __restrict__ kde,
                                              const float* __restrict__ repl,
                                              const float* __restrict__ scale_p,
                                              const float* __restrict__ coef_p,
                                              float* __restrict__ out) {
    const int f  = threadIdx.x;
    const int r0 = blockIdx.x * ROWS_PER_BLOCK;

    float scale, coef;
    if constexpr (INLINE_STATS) {
        // Fallback when workspace is unavailable: recompute per-feature stats.
        float s = 0.f;
        for (int n = 0; n < N; ++n) s += kde[n * F + f];
        const float mean = s * (1.0f / N);
        float ss = 0.f;
        for (int n = 0; n < N; ++n) {
            const float d = kde[n * F + f] - mean;
            ss = fmaf(d, d, ss);
        }
        const float bw = FACTOR * sqrtf(ss * (1.0f / (N - 1)));
        scale = SCALE_C / bw;
        coef  = INV_SQRT_2PI / bw;
    } else {
        scale = scale_p[f];
        coef  = coef_p[f];
    }

    float xv[ROWS_PER_BLOCK], t[ROWS_PER_BLOCK], acc[ROWS_PER_BLOCK];
#pragma unroll
    for (int k = 0; k < ROWS_PER_BLOCK; ++k) {
        xv[k]  = x[(r0 + k) * F + f];
        t[k]   = xv[k] * scale;
        acc[k] = 0.f;
    }

#pragma unroll 4
    for (int n = 0; n < N; ++n) {
        const float ad = kde[n * F + f] * scale;
#pragma unroll
        for (int k = 0; k < ROWS_PER_BLOCK; ++k) {
            const float z = t[k] - ad;
            acc[k] += __builtin_amdgcn_exp2f(-(z * z));
        }
    }

    const float rv = repl[f];
#pragma unroll
    for (int k = 0; k < ROWS_PER_BLOCK; ++k) {
        // Match reference rounding order: mean first (exact *1/128), then *coef.
        const float dens = (acc[k] * (1.0f / N)) * coef;
        out[(r0 + k) * F + f] = (dens >= PROB_THRESHOLD) ? rv : xv[k];
    }
}

extern "C" void kernel_launch(void* const* d_in, const int* in_sizes, int n_in,
                              void* d_out, int out_size, void* d_ws, size_t ws_size,
                              hipStream_t stream) {
    const float* x    = (const float*)d_in[0];
    const float* kde  = (const float*)d_in[1];
    const float* repl = (const float*)d_in[2];
    float* out        = (float*)d_out;

    const int rows = in_sizes[0] / F;           // B*S = 2048
    const int grid = rows / ROWS_PER_BLOCK;     // 512 blocks

    if (ws_size >= 2 * F * sizeof(float)) {
        float* scale = (float*)d_ws;
        float* coef  = scale + F;
        kde_stats<<<1, F, 0, stream>>>(kde, scale, coef);
        kde_mask<false><<<grid, F, 0, stream>>>(x, kde, repl, scale, coef, out);
    } else {
        kde_mask<true><<<grid, F, 0, stream>>>(x, kde, repl, nullptr, nullptr, out);
    }
}

// Round 2
// 28.895 us; speedup vs baseline: 1.0770x; 1.0770x over previous
//
#include <hip/hip_runtime.h>
#include <math.h>

// Problem constants (from reference setup_inputs): B=2, S=1024, F=512, N=128.
#define F 512
#define N 128

constexpr float PROB_THRESHOLD = 0.3f;
constexpr float INV_SQRT_2PI   = 0.3989422804014327f;
// exp(-0.5*z^2) = exp2(-(z*SCALE_C)^2), SCALE_C = sqrt(0.5*log2(e))
constexpr float SCALE_C = 0.8493218002880191f;
// 128^(-0.2)  (Scott's rule factor)
constexpr float FACTOR  = 0.37892914162759955f;

// ---------------------------------------------------------------------------
// Kernel 1: per-feature stats, one WAVE per feature (512 waves across chip).
// Lane l holds kde[l][f] and kde[l+64][f] in registers; two-pass variance via
// butterfly shuffle reductions — no re-reads, ~2 loads + 2 stores per lane.
// Also writes the pre-scaled KDE table a[n][f] = kde[n][f] * scale[f].
// ---------------------------------------------------------------------------
__global__ __launch_bounds__(512) void kde_stats(const float* __restrict__ kde,
                                                 float* __restrict__ a,
                                                 float* __restrict__ scale_o,
                                                 float* __restrict__ coef_o) {
    const int lane = threadIdx.x & 63;
    const int f    = blockIdx.x * 8 + (threadIdx.x >> 6);  // one wave per feature

    const float v0 = kde[lane * F + f];
    const float v1 = kde[(lane + 64) * F + f];

    float s = v0 + v1;
#pragma unroll
    for (int off = 32; off >= 1; off >>= 1) s += __shfl_xor(s, off);
    const float mean = s * (1.0f / N);

    const float d0 = v0 - mean, d1 = v1 - mean;
    float ss = fmaf(d0, d0, d1 * d1);
#pragma unroll
    for (int off = 32; off >= 1; off >>= 1) ss += __shfl_xor(ss, off);

    const float var   = ss * (1.0f / (N - 1));
    const float bw    = FACTOR * sqrtf(var);
    const float scale = SCALE_C / bw;

    a[lane * F + f]        = v0 * scale;
    a[(lane + 64) * F + f] = v1 * scale;
    if (lane == 0) {
        scale_o[f] = scale;
        coef_o[f]  = INV_SQRT_2PI / bw;
    }
}

// ---------------------------------------------------------------------------
// Kernel 2: main KDE-mask kernel. Block = 512 threads (one per feature),
// ROWS rows per block. grid = 2048/ROWS. ROWS=2 -> 1024 blocks -> 8 waves/SIMD
// (full occupancy) while keeping 2 independent exp chains per thread.
// Inner loop per sample: 1 coalesced L1/L2 load of pre-scaled a, then per row
// sub, mul(neg modifier), v_exp_f32, add.
// ---------------------------------------------------------------------------
#define ROWS 2
__global__ __launch_bounds__(512) void kde_mask(const float* __restrict__ x,
                                                const float* __restrict__ a,
                                                const float* __restrict__ repl,
                                                const float* __restrict__ scale_p,
                                                const float* __restrict__ coef_p,
                                                float* __restrict__ out) {
    const int f  = threadIdx.x;
    const int r0 = blockIdx.x * ROWS;

    const float scale = scale_p[f];
    const float coef  = coef_p[f];

    float xv[ROWS], t[ROWS], acc[ROWS];
#pragma unroll
    for (int k = 0; k < ROWS; ++k) {
        xv[k]  = x[(r0 + k) * F + f];
        t[k]   = xv[k] * scale;
        acc[k] = 0.f;
    }

#pragma unroll 8
    for (int n = 0; n < N; ++n) {
        const float ad = a[n * F + f];
#pragma unroll
        for (int k = 0; k < ROWS; ++k) {
            const float z = t[k] - ad;
            acc[k] += __builtin_amdgcn_exp2f(-(z * z));
        }
    }

    const float rv = repl[f];
#pragma unroll
    for (int k = 0; k < ROWS; ++k) {
        const float dens = (acc[k] * (1.0f / N)) * coef;
        out[(r0 + k) * F + f] = (dens >= PROB_THRESHOLD) ? rv : xv[k];
    }
}

// ---------------------------------------------------------------------------
// Fallback (ws too small): self-contained kernel, recomputes stats per block.
// ---------------------------------------------------------------------------
__global__ __launch_bounds__(512) void kde_mask_inline(const float* __restrict__ x,
                                                       const float* __restrict__ kde,
                                                       const float* __restrict__ repl,
                                                       float* __restrict__ out) {
    const int f  = threadIdx.x;
    const int r0 = blockIdx.x * 4;

    float s = 0.f;
    for (int n = 0; n < N; ++n) s += kde[n * F + f];
    const float mean = s * (1.0f / N);
    float ss = 0.f;
    for (int n = 0; n < N; ++n) {
        const float d = kde[n * F + f] - mean;
        ss = fmaf(d, d, ss);
    }
    const float bw    = FACTOR * sqrtf(ss * (1.0f / (N - 1)));
    const float scale = SCALE_C / bw;
    const float coef  = INV_SQRT_2PI / bw;

    float xv[4], t[4], acc[4];
#pragma unroll
    for (int k = 0; k < 4; ++k) {
        xv[k]  = x[(r0 + k) * F + f];
        t[k]   = xv[k] * scale;
        acc[k] = 0.f;
    }
#pragma unroll 4
    for (int n = 0; n < N; ++n) {
        const float ad = kde[n * F + f] * scale;
#pragma unroll
        for (int k = 0; k < 4; ++k) {
            const float z = t[k] - ad;
            acc[k] += __builtin_amdgcn_exp2f(-(z * z));
        }
    }
    const float rv = repl[f];
#pragma unroll
    for (int k = 0; k < 4; ++k) {
        const float dens = (acc[k] * (1.0f / N)) * coef;
        out[(r0 + k) * F + f] = (dens >= PROB_THRESHOLD) ? rv : xv[k];
    }
}

extern "C" void kernel_launch(void* const* d_in, const int* in_sizes, int n_in,
                              void* d_out, int out_size, void* d_ws, size_t ws_size,
                              hipStream_t stream) {
    const float* x    = (const float*)d_in[0];
    const float* kde  = (const float*)d_in[1];
    const float* repl = (const float*)d_in[2];
    float* out        = (float*)d_out;

    const int rows = in_sizes[0] / F;  // B*S = 2048

    const size_t need = (size_t)(2 * F + N * F) * sizeof(float);
    if (ws_size >= need) {
        float* scale = (float*)d_ws;
        float* coef  = scale + F;
        float* a     = coef + F;        // [N][F] pre-scaled kde
        kde_stats<<<F / 8, 512, 0, stream>>>(kde, a, scale, coef);
        kde_mask<<<rows / ROWS, 512, 0, stream>>>(x, a, repl, scale, coef, out);
    } else {
        kde_mask_inline<<<rows / 4, 512, 0, stream>>>(x, kde, repl, out);
    }
}

// Round 3
// 27.563 us; speedup vs baseline: 1.1290x; 1.0483x over previous
//
#include <hip/hip_runtime.h>
#include <math.h>

// Problem constants (from reference setup_inputs): B=2, S=1024, F=512, N=128.
#define F 512
#define N 128
#define ROWS 4

constexpr float PROB_THRESHOLD = 0.3f;
constexpr float INV_SQRT_2PI   = 0.3989422804014327f;
// exp(-0.5*z^2) = exp2(-(z*SCALE_C)^2), SCALE_C = sqrt(0.5*log2(e))
constexpr float SCALE_C = 0.8493218002880191f;
// 128^(-0.2)  (Scott's rule factor)
constexpr float FACTOR  = 0.37892914162759955f;

// ---------------------------------------------------------------------------
// Kernel 1: per-feature stats, one WAVE per feature.
// Writes ab[n][f] = (a, -a*a) with a = kde[n][f]*scale  (float2, coalesced),
// plus scale[f] and coef[f].
// exp(-0.5((x-k)/bw)^2) = exp2(-(t-a)^2) = exp2(-t^2) * exp2(2t*a - a^2),
// with t = x*scale, a = k*scale.
// ---------------------------------------------------------------------------
__global__ __launch_bounds__(512) void kde_stats(const float* __restrict__ kde,
                                                 float2* __restrict__ ab,
                                                 float* __restrict__ scale_o,
                                                 float* __restrict__ coef_o) {
    const int lane = threadIdx.x & 63;
    const int f    = blockIdx.x * 8 + (threadIdx.x >> 6);  // one wave per feature

    const float v0 = kde[lane * F + f];
    const float v1 = kde[(lane + 64) * F + f];

    float s = v0 + v1;
#pragma unroll
    for (int off = 32; off >= 1; off >>= 1) s += __shfl_xor(s, off);
    const float mean = s * (1.0f / N);

    const float d0 = v0 - mean, d1 = v1 - mean;
    float ss = fmaf(d0, d0, d1 * d1);
#pragma unroll
    for (int off = 32; off >= 1; off >>= 1) ss += __shfl_xor(ss, off);

    const float var   = ss * (1.0f / (N - 1));
    const float bw    = FACTOR * sqrtf(var);
    const float scale = SCALE_C / bw;

    const float a0 = v0 * scale;
    const float a1 = v1 * scale;
    ab[lane * F + f]        = make_float2(a0, -(a0 * a0));
    ab[(lane + 64) * F + f] = make_float2(a1, -(a1 * a1));
    if (lane == 0) {
        scale_o[f] = scale;
        coef_o[f]  = INV_SQRT_2PI / bw;
    }
}

// ---------------------------------------------------------------------------
// Kernel 2: main kernel. Block = 512 threads (one per feature), ROWS=4 rows
// per block -> grid 512, 4 waves/SIMD, ILP=4 independent exp chains.
// Inner loop per sample n: 1 dwordx2 load + per row {1 fma, 1 v_exp_f32,
// 1 add}. Trans-pipe-bound by design.
// ---------------------------------------------------------------------------
__global__ __launch_bounds__(512) void kde_mask(const float* __restrict__ x,
                                                const float2* __restrict__ ab,
                                                const float* __restrict__ repl,
                                                const float* __restrict__ scale_p,
                                                const float* __restrict__ coef_p,
                                                float* __restrict__ out) {
    const int f  = threadIdx.x;
    const int r0 = blockIdx.x * ROWS;

    const float scale = scale_p[f];
    const float coef  = coef_p[f];

    float xv[ROWS], t2[ROWS], et[ROWS], acc[ROWS];
#pragma unroll
    for (int k = 0; k < ROWS; ++k) {
        xv[k]  = x[(r0 + k) * F + f];
        const float t = xv[k] * scale;
        t2[k]  = t + t;
        et[k]  = __builtin_amdgcn_exp2f(-(t * t));
        acc[k] = 0.f;
    }

#pragma unroll 8
    for (int n = 0; n < N; ++n) {
        const float2 p = ab[n * F + f];
#pragma unroll
        for (int k = 0; k < ROWS; ++k) {
            acc[k] += __builtin_amdgcn_exp2f(fmaf(t2[k], p.x, p.y));
        }
    }

    const float rv = repl[f];
#pragma unroll
    for (int k = 0; k < ROWS; ++k) {
        const float sum  = acc[k] * et[k];
        const float dens = (sum * (1.0f / N)) * coef;
        out[(r0 + k) * F + f] = (dens >= PROB_THRESHOLD) ? rv : xv[k];
    }
}

// ---------------------------------------------------------------------------
// Fallback (ws too small): self-contained kernel, known-good direct form.
// ---------------------------------------------------------------------------
__global__ __launch_bounds__(512) void kde_mask_inline(const float* __restrict__ x,
                                                       const float* __restrict__ kde,
                                                       const float* __restrict__ repl,
                                                       float* __restrict__ out) {
    const int f  = threadIdx.x;
    const int r0 = blockIdx.x * 4;

    float s = 0.f;
    for (int n = 0; n < N; ++n) s += kde[n * F + f];
    const float mean = s * (1.0f / N);
    float ss = 0.f;
    for (int n = 0; n < N; ++n) {
        const float d = kde[n * F + f] - mean;
        ss = fmaf(d, d, ss);
    }
    const float bw    = FACTOR * sqrtf(ss * (1.0f / (N - 1)));
    const float scale = SCALE_C / bw;
    const float coef  = INV_SQRT_2PI / bw;

    float xv[4], t[4], acc[4];
#pragma unroll
    for (int k = 0; k < 4; ++k) {
        xv[k]  = x[(r0 + k) * F + f];
        t[k]   = xv[k] * scale;
        acc[k] = 0.f;
    }
#pragma unroll 4
    for (int n = 0; n < N; ++n) {
        const float ad = kde[n * F + f] * scale;
#pragma unroll
        for (int k = 0; k < 4; ++k) {
            const float z = t[k] - ad;
            acc[k] += __builtin_amdgcn_exp2f(-(z * z));
        }
    }
    const float rv = repl[f];
#pragma unroll
    for (int k = 0; k < 4; ++k) {
        const float dens = (acc[k] * (1.0f / N)) * coef;
        out[(r0 + k) * F + f] = (dens >= PROB_THRESHOLD) ? rv : xv[k];
    }
}

extern "C" void kernel_launch(void* const* d_in, const int* in_sizes, int n_in,
                              void* d_out, int out_size, void* d_ws, size_t ws_size,
                              hipStream_t stream) {
    const float* x    = (const float*)d_in[0];
    const float* kde  = (const float*)d_in[1];
    const float* repl = (const float*)d_in[2];
    float* out        = (float*)d_out;

    const int rows = in_sizes[0] / F;  // B*S = 2048

    const size_t need = (size_t)(2 * F) * sizeof(float) + (size_t)(N * F) * sizeof(float2);
    if (ws_size >= need) {
        float*  scale = (float*)d_ws;
        float*  coef  = scale + F;
        float2* ab    = (float2*)(coef + F);   // [N][F] (a, -a^2)
        kde_stats<<<F / 8, 512, 0, stream>>>(kde, ab, scale, coef);
        kde_mask<<<rows / ROWS, 512, 0, stream>>>(x, ab, repl, scale, coef, out);
    } else {
        kde_mask_inline<<<rows / 4, 512, 0, stream>>>(x, kde, repl, out);
    }
}

// Round 4
// 27.018 us; speedup vs baseline: 1.1518x; 1.0202x over previous
//
#include <hip/hip_runtime.h>
#include <math.h>

// Problem constants (from reference setup_inputs): B=2, S=1024, F=512, N=128.
#define F 512
#define N 128
#define ROWS 4

constexpr float PROB_THRESHOLD = 0.3f;
constexpr float INV_SQRT_2PI   = 0.3989422804014327f;
// exp(-0.5*z^2) = exp2(-(z*SCALE_C)^2), SCALE_C = sqrt(0.5*log2(e))
constexpr float SCALE_C = 0.8493218002880191f;
// 128^(-0.2)  (Scott's rule factor)
constexpr float FACTOR  = 0.37892914162759955f;

// ---------------------------------------------------------------------------
// Single fused kernel. Block = 512 threads (one per feature), ROWS rows per
// block, grid = 2048/ROWS = 512 -> 2 blocks/CU, 4 waves/SIMD.
//
// Phase 1 (prologue, per thread): one-pass mean/var over this feature's kde
// column (128 coalesced loads; kde is 256 KB -> L2/L3-hot).
//   var = (ss - s*mean)/(N-1); bw = FACTOR*sqrt(var)
//   scale = SCALE_C/bw; coef = INV_SQRT_2PI/bw
//
// Phase 2 (main): factored Gauss transform,
//   exp2(-(t-a)^2) = exp2(-t^2) * exp2(2t*a - a^2),
// inner loop per sample n: 1 load, 1 mul, 1 mul(neg), then per row
// {fma, v_exp_f32, add}. Decision: dens >= 0.3 ? repl : x.
// ---------------------------------------------------------------------------
__global__ __launch_bounds__(512) void kde_mask_fused(const float* __restrict__ x,
                                                      const float* __restrict__ kde,
                                                      const float* __restrict__ repl,
                                                      float* __restrict__ out) {
    const int f  = threadIdx.x;
    const int r0 = blockIdx.x * ROWS;

    // ---- Phase 1: per-feature stats (one-pass) ----
    float s = 0.f, ss = 0.f;
#pragma unroll 8
    for (int n = 0; n < N; ++n) {
        const float v = kde[n * F + f];
        s += v;
        ss = fmaf(v, v, ss);
    }
    const float mean  = s * (1.0f / N);
    const float var   = (ss - s * mean) * (1.0f / (N - 1));
    const float bw    = FACTOR * sqrtf(var);
    const float scale = SCALE_C / bw;
    const float coef  = INV_SQRT_2PI / bw;

    // ---- Phase 2: KDE evaluation + mask ----
    float xv[ROWS], t2[ROWS], et[ROWS], acc[ROWS];
#pragma unroll
    for (int k = 0; k < ROWS; ++k) {
        xv[k]  = x[(r0 + k) * F + f];
        const float t = xv[k] * scale;
        t2[k]  = t + t;
        et[k]  = __builtin_amdgcn_exp2f(-(t * t));
        acc[k] = 0.f;
    }

#pragma unroll 8
    for (int n = 0; n < N; ++n) {
        const float v   = kde[n * F + f];      // second pass: L2-hot
        const float a   = v * scale;
        const float na2 = -(a * a);
#pragma unroll
        for (int k = 0; k < ROWS; ++k) {
            acc[k] += __builtin_amdgcn_exp2f(fmaf(t2[k], a, na2));
        }
    }

    const float rv = repl[f];
#pragma unroll
    for (int k = 0; k < ROWS; ++k) {
        const float sum  = acc[k] * et[k];
        const float dens = (sum * (1.0f / N)) * coef;
        out[(r0 + k) * F + f] = (dens >= PROB_THRESHOLD) ? rv : xv[k];
    }
}

extern "C" void kernel_launch(void* const* d_in, const int* in_sizes, int n_in,
                              void* d_out, int out_size, void* d_ws, size_t ws_size,
                              hipStream_t stream) {
    const float* x    = (const float*)d_in[0];
    const float* kde  = (const float*)d_in[1];
    const float* repl = (const float*)d_in[2];
    float* out        = (float*)d_out;

    const int rows = in_sizes[0] / F;  // B*S = 2048
    kde_mask_fused<<<rows / ROWS, 512, 0, stream>>>(x, kde, repl, out);
}